// Round 1
// baseline (8683.286 us; speedup 1.0000x reference)
//
#include <hip/hip_runtime.h>
#include <cfloat>
#include <cstdint>

// ---------------- problem constants ----------------
#define HID_   512
#define NH_    2
#define E_     256
#define L1_    100
#define SK1_   25
#define U1_    25
#define L2_    21
#define SK2_   12
#define U2_    12
#define BT_    768
#define DLN_   6144   // 12*HID
#define NGATE_ 4096   // 4*2*HID
#define HC_    1024   // 2*HID

// =====================================================================
// Generic fp32 GEMM:  Y[m,n] = sum_k X[m,:K]·W[n,:K] + bias[n]
// Both operands K-contiguous ("NT"). 64x64 tile, BK=16, 256 thr, 4x4 micro.
// Optional batching (grid.z): per-z offsets xoff=(z>>1)*bxn+(z&1)*bxh (same
// for W), yoff=z*byz.  conv_rows!=0 remaps X row r -> ((r/21)*25+r%21)*ldx
// (the overlapped-window conv2 addressing).
// =====================================================================
__global__ __launch_bounds__(256)
void gemm_kernel(const float* __restrict__ X, const float* __restrict__ W,
                 const float* __restrict__ bias, float* __restrict__ Y,
                 int M, int N, int K, int ldx, int ldw, int ldy,
                 size_t bxn, size_t bxh, size_t bwn, size_t bwh, size_t byz,
                 int conv_rows)
{
    __shared__ __align__(16) float Xs[16][68];
    __shared__ __align__(16) float Ws[16][68];
    const int tid = threadIdx.x;
    const int z = blockIdx.z;
    const float* Xb = X + (size_t)(z >> 1) * bxn + (size_t)(z & 1) * bxh;
    const float* Wb = W + (size_t)(z >> 1) * bwn + (size_t)(z & 1) * bwh;
    float* Yb = Y + (size_t)z * byz;
    const int row0 = blockIdx.x * 64;
    const int col0 = blockIdx.y * 64;
    const int lr = tid >> 4;   // 0..15 (row group for loads / row group for compute)
    const int lc = tid & 15;   // k within chunk / col group for compute
    float acc[4][4] = {{0.f}};
    for (int k0 = 0; k0 < K; k0 += 16) {
#pragma unroll
        for (int p = 0; p < 4; ++p) {
            int r = lr + p * 16;
            int gr = row0 + r;
            int gc = col0 + r;
            float xv = 0.f, wv = 0.f;
            if (gr < M) {
                size_t ro = conv_rows ? ((size_t)(gr / 21) * 25 + (size_t)(gr % 21)) * (size_t)ldx
                                      : (size_t)gr * (size_t)ldx;
                xv = Xb[ro + k0 + lc];
            }
            if (gc < N) wv = Wb[(size_t)gc * (size_t)ldw + k0 + lc];
            Xs[lc][r] = xv;
            Ws[lc][r] = wv;
        }
        __syncthreads();
#pragma unroll
        for (int k = 0; k < 16; ++k) {
            float4 a4 = *reinterpret_cast<const float4*>(&Xs[k][lr * 4]);
            float4 b4 = *reinterpret_cast<const float4*>(&Ws[k][lc * 4]);
            float a[4] = {a4.x, a4.y, a4.z, a4.w};
            float b[4] = {b4.x, b4.y, b4.z, b4.w};
#pragma unroll
            for (int i = 0; i < 4; ++i)
#pragma unroll
                for (int j = 0; j < 4; ++j)
                    acc[i][j] += a[i] * b[j];
        }
        __syncthreads();
    }
#pragma unroll
    for (int i = 0; i < 4; ++i) {
        int gr = row0 + lr * 4 + i;
        if (gr >= M) continue;
#pragma unroll
        for (int j = 0; j < 4; ++j) {
            int gc = col0 + lc * 4 + j;
            if (gc >= N) continue;
            float v = acc[i][j];
            if (bias) v += bias[gc];
            Yb[(size_t)gr * (size_t)ldy + gc] = v;
        }
    }
}

// =====================================================================
// conv1: input (768,104,10,8) select wt + positional enc -> VALID conv K=5
// one block per (nloc,l); 512 outputs, 50-tap dot from LDS.
// =====================================================================
__global__ __launch_bounds__(256)
void conv1_kernel(const float* __restrict__ input, const int* __restrict__ wtp,
                  const float* __restrict__ w, const float* __restrict__ bias,
                  float* __restrict__ H, int n0)
{
    __shared__ float xs[50];
    const int bid = blockIdx.x;
    const int nloc = bid / L1_;
    const int l = bid % L1_;
    const size_t n = (size_t)n0 + nloc;
    const int tid = threadIdx.x;
    if (tid < 50) {
        int i = tid / 5, k = tid % 5;
        int t = l + k;
        float xv;
        if (i < 8) {
            xv = input[((n * 104 + t) * 10 + wtp[0]) * 8 + i];
        } else {
            float pos = (float)t / 104.0f;
            xv = (i == 8) ? sinf(pos) : cosf(pos);
        }
        xs[i * 5 + k] = xv;
    }
    __syncthreads();
    for (int o = tid; o < HID_; o += 256) {
        const float* wr = w + (size_t)o * 50;
        float acc = bias[o];
#pragma unroll
        for (int j = 0; j < 50; ++j) acc += wr[j] * xs[j];
        H[((size_t)nloc * L1_ + l) * HID_ + o] = acc;
    }
}

// cumsum V along seq per channel (layout (NC, L, 512))
__global__ void cumsum_kernel(float* __restrict__ V, int L, int total)
{
    int idx = blockIdx.x * 256 + threadIdx.x;
    if (idx >= total) return;
    int n = idx >> 9, c = idx & 511;
    float* p = V + (size_t)n * L * HID_ + c;
    float a = 0.f;
    for (int l = 0; l < L; ++l) { a += p[(size_t)l * HID_]; p[(size_t)l * HID_] = a; }
}

// =====================================================================
// sparsity measure m + stable descending top-U (matches jax.lax.top_k)
// one block per (n,h) = z;  S layout (z, L, L)
// =====================================================================
__global__ __launch_bounds__(128)
void mtop_kernel(const float* __restrict__ S, const int* __restrict__ idx,
                 int* __restrict__ top, int L, int SK, int U)
{
    __shared__ float mv[128];
    __shared__ float rv[128];
    __shared__ int   ri[128];
    const int z = blockIdx.x;
    const int tid = threadIdx.x;
    float m = -FLT_MAX;
    if (tid < L) {
        const float* row = S + ((size_t)z * L + tid) * L;
        float mx = -FLT_MAX, sm = 0.f;
        for (int s = 0; s < SK; ++s) {
            float v = row[idx[tid * SK + s]];
            mx = fmaxf(mx, v);
            sm += v;
        }
        m = mx - sm / (float)L;
    }
    mv[tid] = m;
    __syncthreads();
    for (int u = 0; u < U; ++u) {
        rv[tid] = mv[tid]; ri[tid] = tid;
        __syncthreads();
        for (int off = 64; off > 0; off >>= 1) {
            if (tid < off) {
                float v2 = rv[tid + off]; int i2 = ri[tid + off];
                if (v2 > rv[tid] || (v2 == rv[tid] && i2 < ri[tid])) { rv[tid] = v2; ri[tid] = i2; }
            }
            __syncthreads();
        }
        if (tid == 0) { top[(size_t)z * U + u] = ri[0]; mv[ri[0]] = -FLT_MAX; }
        __syncthreads();
    }
}

// =====================================================================
// softmax(scaled selected score row) @ Vcumsum, written into the
// torch-.view() interleaved layout:  slot=h*U+u -> row slot/2, col (slot&1)*256+e
// one block per (n,h,u); 256 threads (e-dim)
// =====================================================================
__global__ __launch_bounds__(256)
void ctx_kernel(const float* __restrict__ S, const int* __restrict__ top,
                const float* __restrict__ V, float* __restrict__ C,
                int L, int U)
{
    __shared__ float attn[128];
    __shared__ float red[256];
    const int bid = blockIdx.x;
    const int u = bid % U;
    const int rem = bid / U;
    const int h = rem & 1;
    const int n = rem >> 1;
    const int tid = threadIdx.x;
    const int z = n * 2 + h;
    const int r = top[(size_t)z * U + u];
    const float* srow = S + ((size_t)z * L + r) * L;
    float v = (tid < L) ? srow[tid] * 0.0625f : -FLT_MAX;   // 1/sqrt(256)
    red[tid] = v;
    __syncthreads();
    for (int off = 128; off > 0; off >>= 1) { if (tid < off) red[tid] = fmaxf(red[tid], red[tid + off]); __syncthreads(); }
    float mx = red[0];
    __syncthreads();
    float e = (tid < L) ? expf(v - mx) : 0.f;
    red[tid] = e;
    __syncthreads();
    for (int off = 128; off > 0; off >>= 1) { if (tid < off) red[tid] += red[tid + off]; __syncthreads(); }
    float inv = 1.f / red[0];
    if (tid < L) attn[tid] = e * inv;
    __syncthreads();
    float acc = 0.f;
    const float* vb = V + (size_t)n * L * HID_ + h * E_ + tid;
    for (int s = 0; s < L; ++s) acc += attn[s] * vb[(size_t)s * HID_];
    int slot = h * U + u;
    int rr = slot >> 1, cc = (slot & 1) * E_ + tid;
    C[((size_t)n * U + rr) * HID_ + cc] = acc;
}

// 32x32 tiled transpose: A (R,C) -> At (C,R)
__global__ __launch_bounds__(256)
void transpose_kernel(const float* __restrict__ A, float* __restrict__ At, int R, int C)
{
    __shared__ float ts[32][33];
    int cb = blockIdx.x * 32, rb = blockIdx.y * 32;
    int tx = threadIdx.x & 31, ty = threadIdx.x >> 5;
    for (int i = ty; i < 32; i += 8) ts[i][tx] = A[(size_t)(rb + i) * C + cb + tx];
    __syncthreads();
    for (int i = ty; i < 32; i += 8) At[(size_t)(cb + i) * R + rb + tx] = ts[tx][i];
}

// conv2 weight (O,I,K) -> (O,K,I)
__global__ void w2t_kernel(const float* __restrict__ w, float* __restrict__ wt)
{
    int idx = blockIdx.x * 256 + threadIdx.x;
    if (idx >= 512 * 5 * 512) return;
    int i = idx & 511;
    int rem = idx >> 9;
    int k = rem % 5;
    int o = rem / 5;
    wt[idx] = w[((size_t)o * 512 + i) * 5 + k];
}

__global__ void biasg_kernel(const float* __restrict__ a, const float* __restrict__ b, float* __restrict__ o)
{
    int i = blockIdx.x * 256 + threadIdx.x;
    if (i < NGATE_) o[i] = a[i] + b[i];
}

// LayerNorm(6144) in place; one block per row
__global__ __launch_bounds__(256)
void ln_kernel(float* __restrict__ X, const float* __restrict__ g, const float* __restrict__ b)
{
    __shared__ float lred[4];
    const int row = blockIdx.x;
    const int tid = threadIdx.x;
    float* x = X + (size_t)row * DLN_;
    float v[24];
#pragma unroll
    for (int i = 0; i < 24; ++i) v[i] = x[tid + i * 256];
    float s = 0.f;
#pragma unroll
    for (int i = 0; i < 24; ++i) s += v[i];
    for (int off = 32; off > 0; off >>= 1) s += __shfl_down(s, off);
    int lane = tid & 63, wid = tid >> 6;
    if (lane == 0) lred[wid] = s;
    __syncthreads();
    float mu = (lred[0] + lred[1] + lred[2] + lred[3]) / (float)DLN_;
    float q = 0.f;
#pragma unroll
    for (int i = 0; i < 24; ++i) { float d = v[i] - mu; q += d * d; }
    for (int off = 32; off > 0; off >>= 1) q += __shfl_down(q, off);
    __syncthreads();
    if (lane == 0) lred[wid] = q;
    __syncthreads();
    float var = (lred[0] + lred[1] + lred[2] + lred[3]) / (float)DLN_;
    float rstd = 1.0f / sqrtf(var + 1e-5f);
#pragma unroll
    for (int i = 0; i < 24; ++i) {
        int c = tid + i * 256;
        x[c] = (v[i] - mu) * rstd * g[c] + b[c];
    }
}

// =====================================================================
// one LSTM time step: G = Gx[t] + hp @ WhhT ; gates i,f,g,o ; 128 blocks.
// thread = (jjl=tid&7, g=(tid>>3)&3, ks=tid>>5); all 16 batch rows per thread.
// =====================================================================
__global__ __launch_bounds__(256)
void lstm_step_kernel(const float* __restrict__ Gx, const float* __restrict__ WhhT,
                      const float* __restrict__ hp, const float* __restrict__ cp,
                      float* __restrict__ hn, float* __restrict__ cn, int t)
{
    __shared__ __align__(16) float hs[16 * HC_];
    __shared__ float pbuf[4096];
    const int tid = threadIdx.x;
    {
        const float4* hp4 = (const float4*)hp;
        float4* hs4 = (float4*)hs;
        for (int i = tid; i < 16 * HC_ / 4; i += 256) hs4[i] = hp4[i];
    }
    __syncthreads();
    const int jjl = tid & 7;
    const int g = (tid >> 3) & 3;
    const int ks = tid >> 5;                 // 0..7, 128 k each
    const int jj = blockIdx.x * 8 + jjl;     // gridDim.x = 128
    float acc[16];
#pragma unroll
    for (int b = 0; b < 16; ++b) acc[b] = 0.f;
    const float* wp = WhhT + (size_t)(ks * 128) * NGATE_ + (size_t)g * HC_ + jj;
    const float* hb = hs + ks * 128;
    for (int k = 0; k < 128; ++k) {
        float w = wp[(size_t)k * NGATE_];
#pragma unroll
        for (int b = 0; b < 16; ++b) acc[b] += hb[b * HC_ + k] * w;
    }
#pragma unroll
    for (int b = 0; b < 16; ++b) pbuf[((g * 8 + jjl) * 16 + b) * 8 + ks] = acc[b];
    __syncthreads();
    if (tid < 128) {
        int b = tid >> 3, jl = tid & 7;
        int jjo = blockIdx.x * 8 + jl;
        float G[4];
#pragma unroll
        for (int g2 = 0; g2 < 4; ++g2) {
            float s = 0.f;
#pragma unroll
            for (int k2 = 0; k2 < 8; ++k2) s += pbuf[((g2 * 8 + jl) * 16 + b) * 8 + k2];
            G[g2] = s + Gx[((size_t)(b * 48 + t)) * NGATE_ + g2 * HC_ + jjo];
        }
        float ig = 1.f / (1.f + expf(-G[0]));
        float fg = 1.f / (1.f + expf(-G[1]));
        float gg = tanhf(G[2]);
        float og = 1.f / (1.f + expf(-G[3]));
        float c = fg * cp[b * HC_ + jjo] + ig * gg;
        float h = og * tanhf(c);
        cn[b * HC_ + jjo] = c;
        hn[b * HC_ + jjo] = h;
    }
}

// out[b,p] = hn[b]·fin_w[p] + fin_b[p]; one wave per output
__global__ __launch_bounds__(64)
void final_kernel(const float* __restrict__ hn, const float* __restrict__ W,
                  const float* __restrict__ bias, float* __restrict__ out)
{
    int o = blockIdx.x;          // 16*24
    int bb = o / 24, p = o % 24;
    int lane = threadIdx.x;
    float acc = 0.f;
    for (int k = lane; k < HC_; k += 64) acc += hn[(size_t)bb * HC_ + k] * W[(size_t)p * HC_ + k];
    for (int off = 32; off > 0; off >>= 1) acc += __shfl_down(acc, off);
    if (lane == 0) out[o] = acc + bias[p];
}

// ---------------------------------------------------------------------
struct WSLayout {
    float *O2, *Gx, *WhhT, *w2t, *biasG, *hbuf, *cbuf;
    float *H1, *Q1, *K1, *V1, *S1, *CT1, *O1;
    float *H2, *Q2, *K2, *V2, *S2, *CT2;
    int *top1, *top2;
};

static size_t ws_layout(char* base, size_t NC, WSLayout& w)
{
    size_t off = 0;
    auto A = [&](size_t nfloats) -> float* {
        float* p = (float*)(base + off);
        off += ((nfloats * 4 + 255) & ~(size_t)255);
        return p;
    };
    w.O2 = A((size_t)BT_ * 12 * 512);
    w.Gx = A((size_t)BT_ * NGATE_);
    w.WhhT = A((size_t)HC_ * NGATE_);
    w.w2t = A((size_t)512 * 5 * 512);
    w.biasG = A(NGATE_);
    w.hbuf = A(2 * 16 * HC_);
    w.cbuf = A(2 * 16 * HC_);
    w.H1 = A(NC * 51200); w.Q1 = A(NC * 51200); w.K1 = A(NC * 51200); w.V1 = A(NC * 51200);
    w.S1 = A(NC * 20000); w.CT1 = A(NC * 12800); w.O1 = A(NC * 12800);
    w.H2 = A(NC * 10752); w.Q2 = A(NC * 10752); w.K2 = A(NC * 10752); w.V2 = A(NC * 10752);
    w.S2 = A(NC * 882);  w.CT2 = A(NC * 6144);
    w.top1 = (int*)A(NC * 50);
    w.top2 = (int*)A(NC * 24);
    return off;
}

extern "C" void kernel_launch(void* const* d_in, const int* in_sizes, int n_in,
                              void* d_out, int out_size, void* d_ws, size_t ws_size,
                              hipStream_t stream)
{
    const float* input = (const float*)d_in[0];
    const int*   wtp   = (const int*)d_in[2];
    const int*   idx1  = (const int*)d_in[3];
    const int*   idx2  = (const int*)d_in[4];
    const float* c1w   = (const float*)d_in[5];
    const float* c1b   = (const float*)d_in[6];
    const float* c2w   = (const float*)d_in[7];
    const float* c2b   = (const float*)d_in[8];
    const float* a1qw = (const float*)d_in[9];  const float* a1qb = (const float*)d_in[10];
    const float* a1kw = (const float*)d_in[11]; const float* a1kb = (const float*)d_in[12];
    const float* a1vw = (const float*)d_in[13]; const float* a1vb = (const float*)d_in[14];
    const float* a1ow = (const float*)d_in[15]; const float* a1ob = (const float*)d_in[16];
    const float* a2qw = (const float*)d_in[17]; const float* a2qb = (const float*)d_in[18];
    const float* a2kw = (const float*)d_in[19]; const float* a2kb = (const float*)d_in[20];
    const float* a2vw = (const float*)d_in[21]; const float* a2vb = (const float*)d_in[22];
    const float* a2ow = (const float*)d_in[23]; const float* a2ob = (const float*)d_in[24];
    const float* lng  = (const float*)d_in[25]; const float* lnb = (const float*)d_in[26];
    const float* wih  = (const float*)d_in[27]; const float* whh = (const float*)d_in[28];
    const float* bih  = (const float*)d_in[29]; const float* bhh = (const float*)d_in[30];
    const float* finw = (const float*)d_in[31]; const float* finb = (const float*)d_in[32];
    float* out = (float*)d_out;

    // pick largest batch-chunk that fits ws (all keep GEMM M % 64 == 0)
    static const size_t cand[4] = {384, 192, 128, 64};
    size_t NC = 64;
    WSLayout W;
    for (int i = 0; i < 4; ++i) {
        WSLayout tmp;
        size_t need = ws_layout((char*)d_ws, cand[i], tmp);
        if (need <= ws_size) { NC = cand[i]; break; }
    }
    ws_layout((char*)d_ws, NC, W);

    auto gemm = [&](const float* X, const float* Wt, const float* bias, float* Y,
                    int M, int N, int K, int ldx, int ldw, int ldy,
                    int Z, size_t bxn, size_t bxh, size_t bwn, size_t bwh, size_t byz,
                    int conv_rows) {
        dim3 grid((M + 63) / 64, (N + 63) / 64, Z);
        hipLaunchKernelGGL(gemm_kernel, grid, dim3(256), 0, stream,
                           X, Wt, bias, Y, M, N, K, ldx, ldw, ldy,
                           bxn, bxh, bwn, bwh, byz, conv_rows);
    };

    // one-time (per call) prep
    hipLaunchKernelGGL(transpose_kernel, dim3(HC_ / 32, NGATE_ / 32), dim3(256), 0, stream,
                       whh, W.WhhT, NGATE_, HC_);
    hipLaunchKernelGGL(w2t_kernel, dim3((512 * 5 * 512 + 255) / 256), dim3(256), 0, stream, c2w, W.w2t);
    hipLaunchKernelGGL(biasg_kernel, dim3((NGATE_ + 255) / 256), dim3(256), 0, stream, bih, bhh, W.biasG);

    const int nchunks = BT_ / (int)NC;
    for (int ch = 0; ch < nchunks; ++ch) {
        const int n0 = ch * (int)NC;
        const int M1 = (int)NC * L1_;        // rows for qkv1
        hipLaunchKernelGGL(conv1_kernel, dim3((int)NC * L1_), dim3(256), 0, stream,
                           input, wtp, c1w, c1b, W.H1, n0);
        gemm(W.H1, a1qw, a1qb, W.Q1, M1, 512, 512, 512, 512, 512, 1, 0, 0, 0, 0, 0, 0);
        gemm(W.H1, a1kw, a1kb, W.K1, M1, 512, 512, 512, 512, 512, 1, 0, 0, 0, 0, 0, 0);
        gemm(W.H1, a1vw, a1vb, W.V1, M1, 512, 512, 512, 512, 512, 1, 0, 0, 0, 0, 0, 0);
        hipLaunchKernelGGL(cumsum_kernel, dim3(((int)NC * 512 + 255) / 256), dim3(256), 0, stream,
                           W.V1, L1_, (int)NC * 512);
        gemm(W.Q1, W.K1, nullptr, W.S1, L1_, L1_, E_, 512, 512, L1_, (int)NC * 2,
             (size_t)L1_ * 512, E_, (size_t)L1_ * 512, E_, (size_t)L1_ * L1_, 0);
        hipLaunchKernelGGL(mtop_kernel, dim3((int)NC * 2), dim3(128), 0, stream,
                           W.S1, idx1, W.top1, L1_, SK1_, U1_);
        hipLaunchKernelGGL(ctx_kernel, dim3((int)NC * 2 * U1_), dim3(256), 0, stream,
                           W.S1, W.top1, W.V1, W.CT1, L1_, U1_);
        gemm(W.CT1, a1ow, a1ob, W.O1, (int)NC * U1_, 512, 512, 512, 512, 512, 1, 0, 0, 0, 0, 0, 0);
        // conv2 as GEMM over overlapped windows of O1
        gemm(W.O1, W.w2t, c2b, W.H2, (int)NC * L2_, 512, 2560, 512, 2560, 512, 1, 0, 0, 0, 0, 0, 1);
        const int M2 = (int)NC * L2_;
        gemm(W.H2, a2qw, a2qb, W.Q2, M2, 512, 512, 512, 512, 512, 1, 0, 0, 0, 0, 0, 0);
        gemm(W.H2, a2kw, a2kb, W.K2, M2, 512, 512, 512, 512, 512, 1, 0, 0, 0, 0, 0, 0);
        gemm(W.H2, a2vw, a2vb, W.V2, M2, 512, 512, 512, 512, 512, 1, 0, 0, 0, 0, 0, 0);
        hipLaunchKernelGGL(cumsum_kernel, dim3(((int)NC * 512 + 255) / 256), dim3(256), 0, stream,
                           W.V2, L2_, (int)NC * 512);
        gemm(W.Q2, W.K2, nullptr, W.S2, L2_, L2_, E_, 512, 512, L2_, (int)NC * 2,
             (size_t)L2_ * 512, E_, (size_t)L2_ * 512, E_, (size_t)L2_ * L2_, 0);
        hipLaunchKernelGGL(mtop_kernel, dim3((int)NC * 2), dim3(128), 0, stream,
                           W.S2, idx2, W.top2, L2_, SK2_, U2_);
        hipLaunchKernelGGL(ctx_kernel, dim3((int)NC * 2 * U2_), dim3(256), 0, stream,
                           W.S2, W.top2, W.V2, W.CT2, L2_, U2_);
        gemm(W.CT2, a2ow, a2ob, W.O2 + (size_t)n0 * 12 * 512,
             (int)NC * U2_, 512, 512, 512, 512, 512, 1, 0, 0, 0, 0, 0, 0);
    }

    // LayerNorm (in place on O2 viewed as (768, 6144))
    hipLaunchKernelGGL(ln_kernel, dim3(BT_), dim3(256), 0, stream, W.O2, lng, lnb);
    // hoisted LSTM input transform for all timesteps
    gemm(W.O2, wih, W.biasG, W.Gx, BT_, NGATE_, DLN_, DLN_, DLN_, NGATE_, 1, 0, 0, 0, 0, 0, 0);

    hipMemsetAsync(W.hbuf, 0, 2 * 16 * HC_ * sizeof(float), stream);
    hipMemsetAsync(W.cbuf, 0, 2 * 16 * HC_ * sizeof(float), stream);
    for (int t = 0; t < 48; ++t) {
        float* hp = W.hbuf + (t & 1) * 16 * HC_;
        float* hn = W.hbuf + ((t + 1) & 1) * 16 * HC_;
        float* cp = W.cbuf + (t & 1) * 16 * HC_;
        float* cn = W.cbuf + ((t + 1) & 1) * 16 * HC_;
        hipLaunchKernelGGL(lstm_step_kernel, dim3(128), dim3(256), 0, stream,
                           W.Gx, W.WhhT, hp, cp, hn, cn, t);
    }
    hipLaunchKernelGGL(final_kernel, dim3(16 * 24), dim3(64), 0, stream,
                       W.hbuf, finw, finb, out);
}